// Round 3
// baseline (1098.076 us; speedup 1.0000x reference)
//
#include <hip/hip_runtime.h>
#include <hip/hip_cooperative_groups.h>
#include <cstddef>

namespace cg = cooperative_groups;

#define B_    32
#define N_    1024
#define E_    4096
#define A_    16
#define FIN_  16
#define H_    64
#define MID_  208
#define NODES (B_ * N_)      // 32768
#define NEDGE (B_ * E_)      // 131072
#define ROWS  (B_ * A_ * N_) // 524288
#define AN_   (A_ * N_)      // 16384

__device__ __forceinline__ float readlane_f(float v, int l) {
  return __uint_as_float(__builtin_amdgcn_readlane(__float_as_uint(v), l));
}

typedef __attribute__((ext_vector_type(8))) __bf16 bf16x8;
typedef __attribute__((ext_vector_type(4))) float f32x4;

__device__ __forceinline__ f32x4 mfma16(bf16x8 a, bf16x8 b, f32x4 c) {
  return __builtin_amdgcn_mfma_f32_16x16x32_bf16(a, b, c, 0, 0, 0);
}

// split 8 consecutive fp32 into bf16 hi + lo fragments (error ~2^-18 rel)
__device__ __forceinline__ void cvt8(const float* __restrict__ p, bf16x8& hi, bf16x8& lo) {
  float4 v0 = *(const float4*)p;
  float4 v1 = *(const float4*)(p + 4);
  float vv[8] = {v0.x, v0.y, v0.z, v0.w, v1.x, v1.y, v1.z, v1.w};
#pragma unroll
  for (int i = 0; i < 8; i++) {
    __bf16 h = (__bf16)vv[i];
    hi[i] = h;
    lo[i] = (__bf16)(vv[i] - (float)h);
  }
}

// ---- shared-memory union (max 25.7 KB -> 4 blocks/CU = 103 KB/CU < 160 KB) ----
struct SmemFront { int cnt[1024]; int cur[1024]; int part[256]; int ssrcS[4096]; int loc_s[16]; };
struct SmemLogits { float vaS[MID_ * 16]; float accL[4][8][64]; int loc_s[16]; float redm[4]; float reds[4]; };
struct SmemFin { float utmp[1536 + 192]; float redm[4]; float reds[4]; float bcast[2]; };
union SmemAll {
  SmemFront f;
  SmemLogits l;
  SmemFin fin;
  float xr[MID_];
  float scs[16];
};

// ================= phase bodies (shared between mega kernel and fallback kernels) =================

__device__ __forceinline__ void front_body(int blk, SmemFront& S,
                                           const int* __restrict__ el,
                                           const float* __restrict__ dist,
                                           const int* __restrict__ loc,
                                           const float* __restrict__ W1,
                                           const float* __restrict__ eW,
                                           const float* __restrict__ eb,
                                           const float* __restrict__ b1,
                                           int* __restrict__ rowptr,
                                           int* __restrict__ counts,
                                           int* __restrict__ ssrc,
                                           float* __restrict__ d1row,
                                           float* __restrict__ c2row,
                                           float* __restrict__ e1,
                                           float* __restrict__ cu,
                                           float* __restrict__ base,
                                           __bf16* __restrict__ W1BTh,
                                           __bf16* __restrict__ W1BTl) {
  int t = threadIdx.x;
  if (blk < 32) {
    int b = blk;
    for (int i = t; i < 1024; i += 256) S.cnt[i] = 0;
    __syncthreads();
    const int* srcp = el + b * (2 * E_);
    const int* dstp = srcp + E_;
    for (int i = t; i < E_; i += 256) atomicAdd(&S.cnt[dstp[i]], 1);
    __syncthreads();
    int4 c4 = *(const int4*)&S.cnt[t * 4];
    int s = c4.x + c4.y + c4.z + c4.w;
    S.part[t] = s;
    __syncthreads();
    for (int off = 1; off < 256; off <<= 1) {
      int v = (t >= off) ? S.part[t - off] : 0;
      __syncthreads();
      S.part[t] += v;
      __syncthreads();
    }
    int prev = (t == 0) ? 0 : S.part[t - 1];
    int p0 = prev, p1 = p0 + c4.x, p2 = p1 + c4.y, p3 = p2 + c4.z;
    *(int4*)&rowptr[b * 1024 + t * 4] = make_int4(p0 + b * E_, p1 + b * E_, p2 + b * E_, p3 + b * E_);
    *(int4*)&counts[b * 1024 + t * 4] = c4;
    S.cur[t * 4 + 0] = p0;
    S.cur[t * 4 + 1] = p1;
    S.cur[t * 4 + 2] = p2;
    S.cur[t * 4 + 3] = p3;
    __syncthreads();
    for (int i = t; i < E_; i += 256) {
      int dl = dstp[i];
      int sl = srcp[i];
      int pos = atomicAdd(&S.cur[dl], 1);
      S.ssrcS[pos] = b * N_ + sl;
    }
    __syncthreads();
    for (int i = t; i < E_; i += 256) ssrc[b * E_ + i] = S.ssrcS[i];
  } else if (blk < 288) {
    int lane = t & 63, w = t >> 6;
    int r = (blk - 32) * 4 + w;
    const float* dr = dist + (size_t)r * N_;
    float s = 0.f, c2 = 0.f;
#pragma unroll
    for (int k = 0; k < 16; k++) {
      float v = dr[lane + 64 * k];
      s += v;
      c2 = fmaf(v, v, c2);
    }
#pragma unroll
    for (int o = 32; o > 0; o >>= 1) { s += __shfl_xor(s, o); c2 += __shfl_xor(c2, o); }
    if (lane == 0) { d1row[r] = s; c2row[r] = c2; }
  } else if (blk < 320) {
    int b = blk - 288;
    if (t < 16) S.loc_s[t] = loc[b * 16 + t];
    __syncthreads();
    float e4[4] = {0.f, 0.f, 0.f, 0.f};
    for (int a = 0; a < 16; a++) {
      const float* dr = dist + (size_t)S.loc_s[a] * N_;
#pragma unroll
      for (int k = 0; k < 4; k++) e4[k] += dr[t + 256 * k];
    }
#pragma unroll
    for (int k = 0; k < 4; k++) e1[b * N_ + t + 256 * k] = e4[k];
  } else if (blk == 320) {
    int j = t;
    if (j < MID_) {
      float c = 0.f, bs = 0.f;
      for (int k = 0; k < H_; k++) {
        float w = W1[(2 * MID_ + k) * MID_ + j];
        c = fmaf(eW[k], w, c);
        bs = fmaf(eb[k], w, bs);
      }
      cu[j] = c;
      base[j] = bs + b1[j];
    }
  } else if (blk < 529) {
    // W1B^T conversion to bf16 hi/lo, row j = blk-321, k padded to 224 with zeros
    int jr = blk - 321;
    if (t < 224) {
      float v = (t < MID_) ? W1[(size_t)(MID_ + t) * MID_ + jr] : 0.f;
      __bf16 h = (__bf16)v;
      W1BTh[jr * 224 + t] = h;
      W1BTl[jr * 224 + t] = (__bf16)(v - (float)h);
    }
  }
}

template <int FINT, bool COPYIN>
__device__ __forceinline__ void layer_body(int blk,
                                           const float* __restrict__ xin, int xstride, int in_off,
                                           float* __restrict__ xc, int out_off,
                                           const int* __restrict__ rowptr,
                                           const int* __restrict__ counts,
                                           const int* __restrict__ ssrc,
                                           const float* __restrict__ W,
                                           const float* __restrict__ bias,
                                           const float* __restrict__ g,
                                           const float* __restrict__ beta) {
  int t = threadIdx.x, lane = t & 63, w = t >> 6;
  float Wcol[FINT];
#pragma unroll
  for (int f = 0; f < FINT; f++) Wcol[f] = W[f * 64 + lane];
  float bv = bias[lane], gv = g[lane], bev = beta[lane];
  constexpr int CH = 64 / FINT;
  int f = lane & (FINT - 1);
  int ch = (FINT == 64) ? 0 : (lane >> 4);
  int xcd = blk & 7, kk = blk >> 3;
  int graph = xcd * 4 + (kk >> 5);
  int nblk = kk & 31;
  int nbase = graph * N_ + nblk * 32 + w * 8;

  float agg[8];
#pragma unroll
  for (int nn = 0; nn < 8; nn++) {
    int node = nbase + nn;
    int r0 = rowptr[node];
    int deg = counts[node];
    float a0 = 0.f, a1 = 0.f, a2 = 0.f, a3 = 0.f;
    int e = ch;
    for (; e + 3 * CH < deg; e += 4 * CH) {
      int s0 = ssrc[r0 + e];
      int s1 = ssrc[r0 + e + CH];
      int s2 = ssrc[r0 + e + 2 * CH];
      int s3 = ssrc[r0 + e + 3 * CH];
      a0 += xin[(size_t)s0 * xstride + in_off + f];
      a1 += xin[(size_t)s1 * xstride + in_off + f];
      a2 += xin[(size_t)s2 * xstride + in_off + f];
      a3 += xin[(size_t)s3 * xstride + in_off + f];
    }
    for (; e < deg; e += CH) {
      int s = ssrc[r0 + e];
      a0 += xin[(size_t)s * xstride + in_off + f];
    }
    agg[nn] = (a0 + a1) + (a2 + a3);
  }

#pragma unroll
  for (int nn = 0; nn < 8; nn++) {
    int node = nbase + nn;
    float aggf = agg[nn];
    float y0 = bv, y1 = 0.f, y2 = 0.f, y3 = 0.f;
#pragma unroll
    for (int l = 0; l < 64; l += 4) {
      y0 = fmaf(readlane_f(aggf, l + 0), Wcol[(l + 0) & (FINT - 1)], y0);
      y1 = fmaf(readlane_f(aggf, l + 1), Wcol[(l + 1) & (FINT - 1)], y1);
      y2 = fmaf(readlane_f(aggf, l + 2), Wcol[(l + 2) & (FINT - 1)], y2);
      y3 = fmaf(readlane_f(aggf, l + 3), Wcol[(l + 3) & (FINT - 1)], y3);
    }
    float y = (y0 + y1) + (y2 + y3);
    float m = y;
#pragma unroll
    for (int o = 32; o > 0; o >>= 1) m += __shfl_xor(m, o);
    m *= (1.f / 64.f);
    float d = y - m;
    float vv = d * d;
#pragma unroll
    for (int o = 32; o > 0; o >>= 1) vv += __shfl_xor(vv, o);
    vv *= (1.f / 64.f);
    float outv = fmaxf(d * rsqrtf(vv + 1e-5f) * gv + bev, 0.f);
    xc[(size_t)node * MID_ + out_off + lane] = outv;
    if (COPYIN) {
      if (lane < FIN_) xc[(size_t)node * MID_ + lane] = xin[(size_t)node * FIN_ + lane];
    }
  }
}

__device__ __forceinline__ void p1_gemm_body(int blk,
                                             const float* __restrict__ xc,
                                             const __bf16* __restrict__ W1BTh,
                                             const __bf16* __restrict__ W1BTl,
                                             const float* __restrict__ e1,
                                             float* __restrict__ pBT,
                                             float* __restrict__ SB1,
                                             float* __restrict__ SB2,
                                             float* __restrict__ SB3) {
  int t = threadIdx.x, lane = t & 63;
  int w = t >> 6;
  int nb = blk * 32;
  int q = lane >> 4, li = lane & 15;
  int jt0 = (w == 0) ? 0 : (w == 1) ? 4 : (w == 2) ? 7 : 10;
  int njt = (w == 0) ? 4 : 3;
  f32x4 zero4 = {0.f, 0.f, 0.f, 0.f};
  f32x4 acc0[4], acc1[4];
#pragma unroll
  for (int i = 0; i < 4; i++) { acc0[i] = zero4; acc1[i] = zero4; }
  const float* xr0 = xc + (size_t)(nb + li) * MID_;
  const float* xr1 = xc + (size_t)(nb + 16 + li) * MID_;
  for (int kc = 0; kc < 7; kc++) {
    int k0 = kc * 32 + q * 8;
    bf16x8 b0h, b0l, b1h, b1l;
    if (k0 < MID_) {
      cvt8(xr0 + k0, b0h, b0l);
      cvt8(xr1 + k0, b1h, b1l);
    } else {
#pragma unroll
      for (int i = 0; i < 8; i++) {
        b0h[i] = (__bf16)0.f; b0l[i] = (__bf16)0.f;
        b1h[i] = (__bf16)0.f; b1l[i] = (__bf16)0.f;
      }
    }
#pragma unroll
    for (int jj = 0; jj < 4; jj++) {
      if (jj < njt) {
        int jt = jt0 + jj;
        bf16x8 ah = *(const bf16x8*)(W1BTh + (size_t)(jt * 16 + li) * 224 + k0);
        bf16x8 al = *(const bf16x8*)(W1BTl + (size_t)(jt * 16 + li) * 224 + k0);
        acc0[jj] = mfma16(ah, b0h, acc0[jj]);
        acc0[jj] = mfma16(ah, b0l, acc0[jj]);
        acc0[jj] = mfma16(al, b0h, acc0[jj]);
        acc1[jj] = mfma16(ah, b1h, acc1[jj]);
        acc1[jj] = mfma16(ah, b1l, acc1[jj]);
        acc1[jj] = mfma16(al, b1h, acc1[jj]);
      }
    }
  }
  float ev0 = e1[nb + li];
  float ev1 = e1[nb + 16 + li];
#pragma unroll
  for (int jj = 0; jj < 4; jj++) {
    if (jj < njt) {
      int jt = jt0 + jj;
#pragma unroll
      for (int r = 0; r < 4; r++) {
        int j = jt * 16 + q * 4 + r;
        float* pb = pBT + (size_t)j * NODES + nb + li;
        pb[0] = acc0[jj][r];
        pb[16] = acc1[jj][r];
      }
      float s1v[4], s2v[4], s3v[4];
#pragma unroll
      for (int r = 0; r < 4; r++) {
        float a0 = acc0[jj][r], a1 = acc1[jj][r];
        s1v[r] = a0 + a1;
        s2v[r] = fmaf(a0, a0, a1 * a1);
        s3v[r] = fmaf(a0, ev0, a1 * ev1);
      }
#pragma unroll
      for (int o = 8; o > 0; o >>= 1) {
#pragma unroll
        for (int r = 0; r < 4; r++) {
          s1v[r] += __shfl_xor(s1v[r], o);
          s2v[r] += __shfl_xor(s2v[r], o);
          s3v[r] += __shfl_xor(s3v[r], o);
        }
      }
      if (li < 4) {
        float g1 = (li == 0) ? s1v[0] : (li == 1) ? s1v[1] : (li == 2) ? s1v[2] : s1v[3];
        float g2 = (li == 0) ? s2v[0] : (li == 1) ? s2v[1] : (li == 2) ? s2v[2] : s2v[3];
        float g3 = (li == 0) ? s3v[0] : (li == 1) ? s3v[1] : (li == 2) ? s3v[2] : s3v[3];
        int j = jt * 16 + q * 4 + li;
        SB1[(size_t)blk * MID_ + j] = g1;
        SB2[(size_t)blk * MID_ + j] = g2;
        SB3[(size_t)blk * MID_ + j] = g3;
      }
    }
  }
}

__device__ __forceinline__ void p1_pa_body(int ab, float* xr,
                                           const float* __restrict__ xc,
                                           const float* __restrict__ W1,
                                           const int* __restrict__ loc,
                                           float* __restrict__ pA) {
  int t = threadIdx.x;
  int b = ab >> 4;
  int node = b * N_ + loc[ab];
  for (int i = t; i < MID_; i += 256) xr[i] = xc[(size_t)node * MID_ + i];
  __syncthreads();
  if (t < MID_) {
    float acc = 0.f;
    for (int i = 0; i < MID_; i++) acc = fmaf(xr[i], W1[i * MID_ + t], acc);
    pA[ab * MID_ + t] = acc;
  }
  __syncthreads();
}

__device__ __forceinline__ void fin_body(int j, SmemFin& S,
                                         const float* __restrict__ SB1,
                                         const float* __restrict__ SB2,
                                         const float* __restrict__ SB3,
                                         const float* __restrict__ pA,
                                         const float* __restrict__ cu,
                                         const float* __restrict__ base,
                                         const float* __restrict__ d1row,
                                         const float* __restrict__ c2row,
                                         const int* __restrict__ loc,
                                         const float* __restrict__ bng,
                                         const float* __restrict__ bnb,
                                         const float* __restrict__ W2,
                                         float* __restrict__ vaT,
                                         float* __restrict__ wpack4) {
  int t = threadIdx.x, lane = t & 63, w = t >> 6;
  float cuj = cu[j], bj = base[j];
  float q1 = 0.f, q2 = 0.f, q3 = 0.f;
#pragma unroll
  for (int c = t * 4; c < t * 4 + 4; c++) {
    q1 += SB1[(size_t)c * MID_ + j];
    q2 += SB2[(size_t)c * MID_ + j];
    q3 += SB3[(size_t)c * MID_ + j];
  }
  float t1 = 0.f, t2 = 0.f, t3 = 0.f;
#pragma unroll
  for (int r = t * 2; r < t * 2 + 2; r++) {
    float pa = pA[r * MID_ + j] + bj;
    t1 += pa;
    t2 = fmaf(pa, pa, t2);
    t3 = fmaf(pa, d1row[loc[r]], t3);
  }
  S.utmp[0 * 256 + t] = q1;
  S.utmp[1 * 256 + t] = q2;
  S.utmp[2 * 256 + t] = q3;
  S.utmp[3 * 256 + t] = t1;
  S.utmp[4 * 256 + t] = t2;
  S.utmp[5 * 256 + t] = t3;
  float p1 = 0.f, p2 = 0.f;
#pragma unroll
  for (int r = t * 2; r < t * 2 + 2; r++) {
    int l = loc[r];
    p1 += d1row[l];
    p2 += c2row[l];
  }
#pragma unroll
  for (int o = 32; o > 0; o >>= 1) { p1 += __shfl_xor(p1, o); p2 += __shfl_xor(p2, o); }
  if (lane == 0) { S.redm[w] = p1; S.reds[w] = p2; }
  __syncthreads();
  if (t < 192) {
    int s = t >> 5, b32 = t & 31;
    float ssum = 0.f;
#pragma unroll
    for (int i = 0; i < 8; i++) ssum += S.utmp[s * 256 + b32 * 8 + i];
    S.utmp[1536 + s * 32 + b32] = ssum;
  }
  __syncthreads();
  if (t == 0) {
    float Sc1 = (S.redm[0] + S.redm[1]) + (S.redm[2] + S.redm[3]);
    float Sc2 = (S.reds[0] + S.reds[1]) + (S.reds[2] + S.reds[3]);
    double T1 = 0, T2 = 0, T3 = 0, cross = 0, sp1 = 0, sp2 = 0, spe = 0;
    for (int b = 0; b < 32; b++) {
      float sq1 = S.utmp[1536 + 0 * 32 + b];
      float sq2 = S.utmp[1536 + 1 * 32 + b];
      float sq3 = S.utmp[1536 + 2 * 32 + b];
      float pt1 = S.utmp[1536 + 3 * 32 + b];
      float pt2 = S.utmp[1536 + 4 * 32 + b];
      float pt3 = S.utmp[1536 + 5 * 32 + b];
      T1 += pt1; T2 += pt2; T3 += pt3;
      cross += (double)pt1 * sq1;
      sp1 += sq1; sp2 += sq2; spe += sq3;
    }
    double s1 = 1024.0 * T1 + 16.0 * sp1 + (double)cuj * Sc1;
    double s2 = 1024.0 * T2 + 16.0 * sp2 + (double)cuj * cuj * Sc2 +
                2.0 * (cross + (double)cuj * (T3 + spe));
    double mu = s1 * (1.0 / (double)ROWS);
    double var = s2 * (1.0 / (double)ROWS) - mu * mu;
    float sc = (float)(1.0 / sqrt(var + 1e-5)) * bng[j];
    float sh = bnb[j] - (float)mu * sc;
    S.bcast[0] = sc;
    S.bcast[1] = sh;
    wpack4[4 * j + 0] = sc;
    wpack4[4 * j + 1] = cuj * sc;
    wpack4[4 * j + 2] = W2[j];
    wpack4[4 * j + 3] = 0.f;
  }
  __syncthreads();
  float sc = S.bcast[0], sh = S.bcast[1];
#pragma unroll
  for (int r = t * 2; r < t * 2 + 2; r++) {
    int b = r >> 4, a = r & 15;
    float pa = pA[r * MID_ + j] + bj;
    vaT[((size_t)b * MID_ + j) * 16 + a] = pa * sc + sh;
  }
  __syncthreads();
}

__device__ __forceinline__ void logits_body(int b, int nt, SmemLogits& S,
                                            const float* __restrict__ pBT,
                                            const float* __restrict__ vaT,
                                            const float* __restrict__ wpack4,
                                            const float* __restrict__ dist,
                                            const int* __restrict__ loc,
                                            const int* __restrict__ mask,
                                            const float* __restrict__ b2,
                                            float* __restrict__ lg,
                                            float2* __restrict__ Psm) {
  int t = threadIdx.x, lane = t & 63;
  int w = __builtin_amdgcn_readfirstlane(t >> 6);
  int n0 = nt * 64;
  if (t < 16) S.loc_s[t] = loc[b * 16 + t];
  for (int i = t; i < MID_ * 16; i += 256) S.vaS[i] = vaT[(size_t)b * MID_ * 16 + i];
  __syncthreads();
  float c[16];
#pragma unroll
  for (int a = 0; a < 16; a++) c[a] = dist[(size_t)S.loc_s[a] * N_ + n0 + lane];
  float acc16[16];
#pragma unroll
  for (int a = 0; a < 16; a++) acc16[a] = 0.f;
  const float4* wp = (const float4*)wpack4;
  int ng = b * N_ + n0 + lane;
  int jb = w * 52;
#pragma unroll 4
  for (int jj = 0; jj < 52; jj++) {
    int j = jb + jj;
    float pbv = pBT[(size_t)j * NODES + ng];
    float4 wv = wp[j];
    float pbs = pbv * wv.x;
    const float* va = &S.vaS[j * 16];
#pragma unroll
    for (int a = 0; a < 16; a++) {
      float h = fmaf(c[a], wv.y, va[a] + pbs);
      h = fmaxf(h, 0.f);
      acc16[a] = fmaf(h, wv.z, acc16[a]);
    }
  }

  float b2v = b2[0];
  float sv[4];
  int ois[4];
  unsigned mk = 0;
#pragma unroll
  for (int half = 0; half < 2; half++) {
#pragma unroll
    for (int a8 = 0; a8 < 8; a8++) S.accL[t >> 6][a8][lane] = acc16[half * 8 + a8];
    __syncthreads();
#pragma unroll
    for (int p = 0; p < 2; p++) {
      int idx = p * 256 + t;
      int a8 = idx >> 6, nn = idx & 63;
      float s = (S.accL[0][a8][nn] + S.accL[1][a8][nn]) +
                (S.accL[2][a8][nn] + S.accL[3][a8][nn]) + b2v;
      int a = half * 8 + a8;
      int oi = b * AN_ + a * N_ + n0 + nn;
      int iv = half * 2 + p;
      bool m_ = mask[oi] != 0;
      sv[iv] = m_ ? s : -1e8f;
      ois[iv] = oi;
      mk |= (m_ ? 1u : 0u) << iv;
    }
    __syncthreads();
  }

  float mx = fmaxf(fmaxf(sv[0], sv[1]), fmaxf(sv[2], sv[3]));
#pragma unroll
  for (int o = 32; o > 0; o >>= 1) mx = fmaxf(mx, __shfl_xor(mx, o));
  if (lane == 0) S.redm[t >> 6] = mx;
  __syncthreads();
  mx = fmaxf(fmaxf(S.redm[0], S.redm[1]), fmaxf(S.redm[2], S.redm[3]));
  float ssum = 0.f;
#pragma unroll
  for (int iv = 0; iv < 4; iv++) {
    float pv = ((mk >> iv) & 1u) ? expf(sv[iv] - mx) : 0.f;
    lg[ois[iv]] = pv;
    ssum += pv;
  }
#pragma unroll
  for (int o = 32; o > 0; o >>= 1) ssum += __shfl_xor(ssum, o);
  if (lane == 0) S.reds[t >> 6] = ssum;
  __syncthreads();
  if (t == 0) Psm[b * 16 + nt] = make_float2(mx, (S.reds[0] + S.reds[1]) + (S.reds[2] + S.reds[3]));
  __syncthreads();
}

__device__ __forceinline__ void sm2_body(int b, int x, float* scs,
                                         const float* __restrict__ lg,
                                         const float2* __restrict__ P,
                                         float* __restrict__ out) {
  int t = threadIdx.x;
  float M = -3.0e38f;
  float2 pr[16];
#pragma unroll
  for (int k = 0; k < 16; k++) {
    pr[k] = P[b * 16 + k];
    M = fmaxf(M, pr[k].x);
  }
  float S = 0.f;
#pragma unroll
  for (int k = 0; k < 16; k++) S += pr[k].y * expf(pr[k].x - M);
  float inv = 1.0f / S;
  if (t < 16) scs[t] = expf(pr[t].x - M) * inv;
  __syncthreads();
  const float* lb = lg + b * AN_ + x * 2048;
  float* ob = out + b * AN_ + x * 2048;
#pragma unroll
  for (int k = 0; k < 8; k++) {
    int i = t + 256 * k;
    int n = (x * 2048 + i) & 1023;
    ob[i] = lb[i] * scs[n >> 6];
  }
}

// ================= single cooperative mega-kernel: 1024 blocks x 256 thr, 7 grid syncs =================
__global__ __launch_bounds__(256, 4) void k_mega(
    const float* gn, const int* el, const int* loc, const int* mask, const float* dist,
    const float* c0W, const float* c0b, const float* c0g, const float* c0be,
    const float* c1W, const float* c1b, const float* c1g, const float* c1be,
    const float* c2W, const float* c2b, const float* c2g, const float* c2be,
    const float* eW, const float* eb, const float* W1, const float* b1,
    const float* bng, const float* bnb, const float* W2, const float* b2,
    int* rowptr, int* counts, int* ssrc, float* xc, float* pBT, float* pA,
    float* cu, float* base, float* d1row, float* c2row, float* e1,
    float* vaT, float* wpack4, float* lg, float2* Psm,
    __bf16* W1BTh, __bf16* W1BTl, float* SB1, float* SB2, float* SB3, float* out) {
  __shared__ SmemAll sm;
  cg::grid_group grid = cg::this_grid();
  int blk = blockIdx.x;

  // P0: front
  front_body(blk, sm.f, el, dist, loc, W1, eW, eb, b1,
             rowptr, counts, ssrc, d1row, c2row, e1, cu, base, W1BTh, W1BTl);
  __syncthreads();
  grid.sync();

  // P1-P3: GIN layers
  layer_body<16, true>(blk, gn, FIN_, 0, xc, 16, rowptr, counts, ssrc, c0W, c0b, c0g, c0be);
  __syncthreads();
  grid.sync();
  layer_body<64, false>(blk, xc, MID_, 16, xc, 80, rowptr, counts, ssrc, c1W, c1b, c1g, c1be);
  __syncthreads();
  grid.sync();
  layer_body<64, false>(blk, xc, MID_, 80, xc, 144, rowptr, counts, ssrc, c2W, c2b, c2g, c2be);
  __syncthreads();
  grid.sync();

  // P4: pBT GEMM (all blocks) + pA (blocks 512..1023)
  p1_gemm_body(blk, xc, W1BTh, W1BTl, e1, pBT, SB1, SB2, SB3);
  if (blk >= 512) p1_pa_body(blk - 512, sm.xr, xc, W1, loc, pA);
  __syncthreads();
  grid.sync();

  // P5: BN finalize
  if (blk < 208) fin_body(blk, sm.fin, SB1, SB2, SB3, pA, cu, base, d1row, c2row,
                          loc, bng, bnb, W2, vaT, wpack4);
  __syncthreads();
  grid.sync();

  // P6: logits + softmax partials
  if (blk < 512) logits_body(blk >> 4, blk & 15, sm.l, pBT, vaT, wpack4, dist, loc, mask, b2, lg, Psm);
  __syncthreads();
  grid.sync();

  // P7: softmax combine
  if (blk < 256) sm2_body(blk >> 3, blk & 7, sm.scs, lg, Psm, out);
}

// ================= fallback kernels (identical bodies, 8-launch path) =================
__global__ __launch_bounds__(256) void k_front(const int* el, const float* dist, const int* loc,
                                               const float* W1, const float* eW, const float* eb,
                                               const float* b1, int* rowptr, int* counts, int* ssrc,
                                               float* d1row, float* c2row, float* e1,
                                               float* cu, float* base, __bf16* W1BTh, __bf16* W1BTl) {
  __shared__ SmemAll sm;
  front_body(blockIdx.x, sm.f, el, dist, loc, W1, eW, eb, b1,
             rowptr, counts, ssrc, d1row, c2row, e1, cu, base, W1BTh, W1BTl);
}

template <int FINT, bool COPYIN>
__global__ __launch_bounds__(256) void k_layer(const float* xin, int xstride, int in_off,
                                               float* xc, int out_off, const int* rowptr,
                                               const int* counts, const int* ssrc, const float* W,
                                               const float* bias, const float* g, const float* beta) {
  layer_body<FINT, COPYIN>(blockIdx.x, xin, xstride, in_off, xc, out_off,
                           rowptr, counts, ssrc, W, bias, g, beta);
}

__global__ __launch_bounds__(256) void k_p1(const float* xc, const float* W1,
                                            const __bf16* W1BTh, const __bf16* W1BTl,
                                            const float* e1, const int* loc,
                                            float* pBT, float* pA,
                                            float* SB1, float* SB2, float* SB3) {
  __shared__ SmemAll sm;
  int blk = blockIdx.x;
  if (blk < 1024) p1_gemm_body(blk, xc, W1BTh, W1BTl, e1, pBT, SB1, SB2, SB3);
  else p1_pa_body(blk - 1024, sm.xr, xc, W1, loc, pA);
}

__global__ __launch_bounds__(256) void k_fin(const float* SB1, const float* SB2, const float* SB3,
                                             const float* pA, const float* cu, const float* base,
                                             const float* d1row, const float* c2row, const int* loc,
                                             const float* bng, const float* bnb, const float* W2,
                                             float* vaT, float* wpack4) {
  __shared__ SmemAll sm;
  fin_body(blockIdx.x, sm.fin, SB1, SB2, SB3, pA, cu, base, d1row, c2row,
           loc, bng, bnb, W2, vaT, wpack4);
}

__global__ __launch_bounds__(256) void k_logits(const float* pBT, const float* vaT,
                                                const float* wpack4, const float* dist,
                                                const int* loc, const int* mask, const float* b2,
                                                float* lg, float2* Psm) {
  __shared__ SmemAll sm;
  logits_body(blockIdx.y, blockIdx.x, sm.l, pBT, vaT, wpack4, dist, loc, mask, b2, lg, Psm);
}

__global__ __launch_bounds__(256) void k_sm2(const float* lg, const float2* P, float* out) {
  __shared__ SmemAll sm;
  sm2_body(blockIdx.y, blockIdx.x, sm.scs, lg, P, out);
}

extern "C" void kernel_launch(void* const* d_in, const int* in_sizes, int n_in,
                              void* d_out, int out_size, void* d_ws, size_t ws_size,
                              hipStream_t stream) {
  const float* gn = (const float*)d_in[0];
  const int* el = (const int*)d_in[1];
  const int* loc = (const int*)d_in[2];
  const int* mask = (const int*)d_in[3];
  const float* dist = (const float*)d_in[4];
  const float* c0W = (const float*)d_in[5];
  const float* c0b = (const float*)d_in[6];
  const float* c0g = (const float*)d_in[7];
  const float* c0be = (const float*)d_in[8];
  const float* c1W = (const float*)d_in[9];
  const float* c1b = (const float*)d_in[10];
  const float* c1g = (const float*)d_in[11];
  const float* c1be = (const float*)d_in[12];
  const float* c2W = (const float*)d_in[13];
  const float* c2b = (const float*)d_in[14];
  const float* c2g = (const float*)d_in[15];
  const float* c2be = (const float*)d_in[16];
  const float* eW = (const float*)d_in[17];
  const float* eb = (const float*)d_in[18];
  const float* W1 = (const float*)d_in[19];
  const float* b1 = (const float*)d_in[20];
  const float* bng = (const float*)d_in[21];
  const float* bnb = (const float*)d_in[22];
  const float* W2 = (const float*)d_in[23];
  const float* b2 = (const float*)d_in[24];
  float* out = (float*)d_out;

  char* p = (char*)d_ws;
  auto alloc = [&](size_t bytes) {
    char* r = p;
    p += (bytes + 255) & ~(size_t)255;
    return r;
  };
  int* counts = (int*)alloc((size_t)NODES * 4);
  int* rowptr = (int*)alloc((size_t)NODES * 4);
  int* ssrc = (int*)alloc((size_t)NEDGE * 4);
  float* xc = (float*)alloc((size_t)NODES * MID_ * 4);
  float* pBT = (float*)alloc((size_t)NODES * MID_ * 4);
  float* pA = (float*)alloc((size_t)512 * MID_ * 4);
  float* cu = (float*)alloc(256 * 4);
  float* base = (float*)alloc(256 * 4);
  float* d1row = (float*)alloc((size_t)N_ * 4);
  float* c2row = (float*)alloc((size_t)N_ * 4);
  float* e1 = (float*)alloc((size_t)B_ * N_ * 4);
  float* vaT = (float*)alloc((size_t)B_ * MID_ * 16 * 4);
  float* wpack4 = (float*)alloc((size_t)MID_ * 4 * 4);
  float* lg = (float*)alloc((size_t)ROWS * 4);
  float2* Psm = (float2*)alloc((size_t)B_ * 16 * 8);
  __bf16* W1BTh = (__bf16*)alloc((size_t)MID_ * 224 * 2);
  __bf16* W1BTl = (__bf16*)alloc((size_t)MID_ * 224 * 2);
  float* SB1 = (float*)alloc((size_t)1024 * MID_ * 4);
  float* SB2 = (float*)alloc((size_t)1024 * MID_ * 4);
  float* SB3 = (float*)alloc((size_t)1024 * MID_ * 4);

  void* kargs[] = {
      (void*)&gn, (void*)&el, (void*)&loc, (void*)&mask, (void*)&dist,
      (void*)&c0W, (void*)&c0b, (void*)&c0g, (void*)&c0be,
      (void*)&c1W, (void*)&c1b, (void*)&c1g, (void*)&c1be,
      (void*)&c2W, (void*)&c2b, (void*)&c2g, (void*)&c2be,
      (void*)&eW, (void*)&eb, (void*)&W1, (void*)&b1,
      (void*)&bng, (void*)&bnb, (void*)&W2, (void*)&b2,
      (void*)&rowptr, (void*)&counts, (void*)&ssrc, (void*)&xc, (void*)&pBT, (void*)&pA,
      (void*)&cu, (void*)&base, (void*)&d1row, (void*)&c2row, (void*)&e1,
      (void*)&vaT, (void*)&wpack4, (void*)&lg, (void*)&Psm,
      (void*)&W1BTh, (void*)&W1BTl, (void*)&SB1, (void*)&SB2, (void*)&SB3, (void*)&out};

  hipError_t err = hipLaunchCooperativeKernel((const void*)k_mega, dim3(1024), dim3(256),
                                              kargs, 0, stream);
  if (err != hipSuccess) {
    (void)hipGetLastError();  // clear sticky error, fall back to the 8-kernel path
    k_front<<<529, 256, 0, stream>>>(el, dist, loc, W1, eW, eb, b1,
                                     rowptr, counts, ssrc, d1row, c2row, e1, cu, base,
                                     W1BTh, W1BTl);
    k_layer<16, true><<<1024, 256, 0, stream>>>(gn, FIN_, 0, xc, 16, rowptr, counts, ssrc, c0W, c0b, c0g, c0be);
    k_layer<64, false><<<1024, 256, 0, stream>>>(xc, MID_, 16, xc, 80, rowptr, counts, ssrc, c1W, c1b, c1g, c1be);
    k_layer<64, false><<<1024, 256, 0, stream>>>(xc, MID_, 80, xc, 144, rowptr, counts, ssrc, c2W, c2b, c2g, c2be);
    k_p1<<<1536, 256, 0, stream>>>(xc, W1, W1BTh, W1BTl, e1, loc, pBT, pA, SB1, SB2, SB3);
    k_fin<<<208, 256, 0, stream>>>(SB1, SB2, SB3, pA, cu, base, d1row, c2row, loc, bng, bnb, W2, vaT, wpack4);
    k_logits<<<dim3(16, 32), 256, 0, stream>>>(pBT, vaT, wpack4, dist, loc, mask, b2, lg, Psm);
    k_sm2<<<dim3(8, 32), 256, 0, stream>>>(lg, Psm, out);
  }
}

// Round 5
// 291.591 us; speedup vs baseline: 3.7658x; 3.7658x over previous
//
#include <hip/hip_runtime.h>
#include <cstddef>

#define B_    32
#define N_    1024
#define E_    4096
#define A_    16
#define FIN_  16
#define H_    64
#define MID_  208
#define NODES (B_ * N_)      // 32768
#define NEDGE (B_ * E_)      // 131072
#define ROWS  (B_ * A_ * N_) // 524288
#define AN_   (A_ * N_)      // 16384

__device__ __forceinline__ float readlane_f(float v, int l) {
  return __uint_as_float(__builtin_amdgcn_readlane(__float_as_uint(v), l));
}

typedef __attribute__((ext_vector_type(8))) __bf16 bf16x8;
typedef __attribute__((ext_vector_type(4))) float f32x4;

__device__ __forceinline__ f32x4 mfma16(bf16x8 a, bf16x8 b, f32x4 c) {
  return __builtin_amdgcn_mfma_f32_16x16x32_bf16(a, b, c, 0, 0, 0);
}

// split 8 consecutive fp32 into bf16 hi + lo fragments (error ~2^-18 rel)
__device__ __forceinline__ void cvt8(const float* __restrict__ p, bf16x8& hi, bf16x8& lo) {
  float4 v0 = *(const float4*)p;
  float4 v1 = *(const float4*)(p + 4);
  float vv[8] = {v0.x, v0.y, v0.z, v0.w, v1.x, v1.y, v1.z, v1.w};
#pragma unroll
  for (int i = 0; i < 8; i++) {
    __bf16 h = (__bf16)vv[i];
    hi[i] = h;
    lo[i] = (__bf16)(vv[i] - (float)h);
  }
}

// ---------------- front: per-graph CSR in-block (LDS-staged ssrc) + d1 + csum + cu + W1B^T->bf16 ----------------
__global__ __launch_bounds__(256) void k_front(const int* __restrict__ el,
                                               const float* __restrict__ dist,
                                               const int* __restrict__ loc,
                                               const float* __restrict__ W1,
                                               const float* __restrict__ eW,
                                               const float* __restrict__ eb,
                                               const float* __restrict__ b1,
                                               int* __restrict__ rowptr,
                                               int* __restrict__ counts,
                                               int* __restrict__ ssrc,
                                               float* __restrict__ d1row,
                                               float* __restrict__ c2row,
                                               float* __restrict__ e1,
                                               float* __restrict__ cu,
                                               float* __restrict__ base,
                                               __bf16* __restrict__ W1BTh,
                                               __bf16* __restrict__ W1BTl,
                                               int* __restrict__ smcnt) {
  __shared__ int cnt[1024];
  __shared__ int cur[1024];
  __shared__ int part[256];
  __shared__ int ssrcS[4096];
  __shared__ int loc_s[16];
  int blk = blockIdx.x, t = threadIdx.x;
  if (blk < 32) {
    int b = blk;
    for (int i = t; i < 1024; i += 256) cnt[i] = 0;
    __syncthreads();
    const int* srcp = el + b * (2 * E_);
    const int* dstp = srcp + E_;
    for (int i = t; i < E_; i += 256) atomicAdd(&cnt[dstp[i]], 1);
    __syncthreads();
    int4 c4 = *(const int4*)&cnt[t * 4];
    int s = c4.x + c4.y + c4.z + c4.w;
    part[t] = s;
    __syncthreads();
    for (int off = 1; off < 256; off <<= 1) {
      int v = (t >= off) ? part[t - off] : 0;
      __syncthreads();
      part[t] += v;
      __syncthreads();
    }
    int prev = (t == 0) ? 0 : part[t - 1];
    int p0 = prev, p1 = p0 + c4.x, p2 = p1 + c4.y, p3 = p2 + c4.z;
    *(int4*)&rowptr[b * 1024 + t * 4] = make_int4(p0 + b * E_, p1 + b * E_, p2 + b * E_, p3 + b * E_);
    *(int4*)&counts[b * 1024 + t * 4] = c4;
    cur[t * 4 + 0] = p0;
    cur[t * 4 + 1] = p1;
    cur[t * 4 + 2] = p2;
    cur[t * 4 + 3] = p3;
    __syncthreads();
    for (int i = t; i < E_; i += 256) {
      int dl = dstp[i];
      int sl = srcp[i];
      int pos = atomicAdd(&cur[dl], 1);
      ssrcS[pos] = b * N_ + sl;
    }
    __syncthreads();
    for (int i = t; i < E_; i += 256) ssrc[b * E_ + i] = ssrcS[i];
  } else if (blk < 288) {
    int lane = t & 63, w = t >> 6;
    int r = (blk - 32) * 4 + w;
    const float* dr = dist + (size_t)r * N_;
    float s = 0.f, c2 = 0.f;
#pragma unroll
    for (int k = 0; k < 16; k++) {
      float v = dr[lane + 64 * k];
      s += v;
      c2 = fmaf(v, v, c2);
    }
#pragma unroll
    for (int o = 32; o > 0; o >>= 1) { s += __shfl_xor(s, o); c2 += __shfl_xor(c2, o); }
    if (lane == 0) { d1row[r] = s; c2row[r] = c2; }
  } else if (blk < 320) {
    int b = blk - 288;
    if (t < 16) loc_s[t] = loc[b * 16 + t];
    __syncthreads();
    float e4[4] = {0.f, 0.f, 0.f, 0.f};
    for (int a = 0; a < 16; a++) {
      const float* dr = dist + (size_t)loc_s[a] * N_;
#pragma unroll
      for (int k = 0; k < 4; k++) e4[k] += dr[t + 256 * k];
    }
#pragma unroll
    for (int k = 0; k < 4; k++) e1[b * N_ + t + 256 * k] = e4[k];
  } else if (blk == 320) {
    int j = t;
    if (j < MID_) {
      float c = 0.f, bs = 0.f;
      for (int k = 0; k < H_; k++) {
        float w = W1[(2 * MID_ + k) * MID_ + j];
        c = fmaf(eW[k], w, c);
        bs = fmaf(eb[k], w, bs);
      }
      cu[j] = c;
      base[j] = bs + b1[j];
    }
    if (j >= 224 && j < 256) smcnt[j - 224] = 0;   // zero the per-batch softmax ticket counters
  } else {
    // W1B^T conversion to bf16 hi/lo, row j = blk-321, k padded to 224 with zeros
    int jr = blk - 321;
    if (t < 224) {
      float v = (t < MID_) ? W1[(size_t)(MID_ + t) * MID_ + jr] : 0.f;
      __bf16 h = (__bf16)v;
      W1BTh[jr * 224 + t] = h;
      W1BTl[jr * 224 + t] = (__bf16)(v - (float)h);
    }
  }
}

// ---------------- GIN layer: XCD-swizzled blocks; wave per 8 nodes ----------------
template <int FINT, bool COPYIN>
__global__ __launch_bounds__(256) void k_layer(const float* __restrict__ xin, int xstride, int in_off,
                                               float* __restrict__ xc, int out_off,
                                               const int* __restrict__ rowptr,
                                               const int* __restrict__ counts,
                                               const int* __restrict__ ssrc,
                                               const float* __restrict__ W,
                                               const float* __restrict__ bias,
                                               const float* __restrict__ g,
                                               const float* __restrict__ beta) {
  int t = threadIdx.x, lane = t & 63, w = t >> 6;
  float Wcol[FINT];
#pragma unroll
  for (int f = 0; f < FINT; f++) Wcol[f] = W[f * 64 + lane];
  float bv = bias[lane], gv = g[lane], bev = beta[lane];
  constexpr int CH = 64 / FINT;
  int f = lane & (FINT - 1);
  int ch = (FINT == 64) ? 0 : (lane >> 4);
  int blk = blockIdx.x;
  int xcd = blk & 7, kk = blk >> 3;
  int graph = xcd * 4 + (kk >> 5);
  int nblk = kk & 31;
  int nbase = graph * N_ + nblk * 32 + w * 8;

  float agg[8];
#pragma unroll
  for (int nn = 0; nn < 8; nn++) {
    int node = nbase + nn;
    int r0 = rowptr[node];
    int deg = counts[node];
    float a0 = 0.f, a1 = 0.f, a2 = 0.f, a3 = 0.f;
    int e = ch;
    for (; e + 3 * CH < deg; e += 4 * CH) {
      int s0 = ssrc[r0 + e];
      int s1 = ssrc[r0 + e + CH];
      int s2 = ssrc[r0 + e + 2 * CH];
      int s3 = ssrc[r0 + e + 3 * CH];
      a0 += xin[(size_t)s0 * xstride + in_off + f];
      a1 += xin[(size_t)s1 * xstride + in_off + f];
      a2 += xin[(size_t)s2 * xstride + in_off + f];
      a3 += xin[(size_t)s3 * xstride + in_off + f];
    }
    for (; e < deg; e += CH) {
      int s = ssrc[r0 + e];
      a0 += xin[(size_t)s * xstride + in_off + f];
    }
    agg[nn] = (a0 + a1) + (a2 + a3);
  }

#pragma unroll
  for (int nn = 0; nn < 8; nn++) {
    int node = nbase + nn;
    float aggf = agg[nn];
    float y0 = bv, y1 = 0.f, y2 = 0.f, y3 = 0.f;
#pragma unroll
    for (int l = 0; l < 64; l += 4) {
      y0 = fmaf(readlane_f(aggf, l + 0), Wcol[(l + 0) & (FINT - 1)], y0);
      y1 = fmaf(readlane_f(aggf, l + 1), Wcol[(l + 1) & (FINT - 1)], y1);
      y2 = fmaf(readlane_f(aggf, l + 2), Wcol[(l + 2) & (FINT - 1)], y2);
      y3 = fmaf(readlane_f(aggf, l + 3), Wcol[(l + 3) & (FINT - 1)], y3);
    }
    float y = (y0 + y1) + (y2 + y3);
    float m = y;
#pragma unroll
    for (int o = 32; o > 0; o >>= 1) m += __shfl_xor(m, o);
    m *= (1.f / 64.f);
    float d = y - m;
    float vv = d * d;
#pragma unroll
    for (int o = 32; o > 0; o >>= 1) vv += __shfl_xor(vv, o);
    vv *= (1.f / 64.f);
    float outv = fmaxf(d * rsqrtf(vv + 1e-5f) * gv + bev, 0.f);
    xc[(size_t)node * MID_ + out_off + lane] = outv;
    if (COPYIN) {
      if (lane < FIN_) xc[(size_t)node * MID_ + lane] = xin[(size_t)node * FIN_ + lane];
    }
  }
}

// ---------------- p1: blk<1024: MFMA GEMM pBT (bf16 hi/lo split) + in-register column stats; blk>=1024: pA ----------------
__global__ __launch_bounds__(256) void k_p1(const float* __restrict__ xc,
                                            const float* __restrict__ W1,
                                            const __bf16* __restrict__ W1BTh,
                                            const __bf16* __restrict__ W1BTl,
                                            const float* __restrict__ e1,
                                            const int* __restrict__ loc,
                                            float* __restrict__ pBT,
                                            float* __restrict__ pA,
                                            float* __restrict__ SB1,
                                            float* __restrict__ SB2,
                                            float* __restrict__ SB3) {
  __shared__ float xr[MID_];
  int t = threadIdx.x, lane = t & 63;
  int w = t >> 6;
  int blk = blockIdx.x;
  if (blk < 1024) {
    int nb = blk * 32;
    int q = lane >> 4, li = lane & 15;
    int jt0 = (w == 0) ? 0 : (w == 1) ? 4 : (w == 2) ? 7 : 10;
    int njt = (w == 0) ? 4 : 3;
    f32x4 zero4 = {0.f, 0.f, 0.f, 0.f};
    f32x4 acc0[4], acc1[4];
#pragma unroll
    for (int i = 0; i < 4; i++) { acc0[i] = zero4; acc1[i] = zero4; }
    const float* xr0 = xc + (size_t)(nb + li) * MID_;
    const float* xr1 = xc + (size_t)(nb + 16 + li) * MID_;
    for (int kc = 0; kc < 7; kc++) {
      int k0 = kc * 32 + q * 8;
      bf16x8 b0h, b0l, b1h, b1l;
      if (k0 < MID_) {
        cvt8(xr0 + k0, b0h, b0l);
        cvt8(xr1 + k0, b1h, b1l);
      } else {
#pragma unroll
        for (int i = 0; i < 8; i++) {
          b0h[i] = (__bf16)0.f; b0l[i] = (__bf16)0.f;
          b1h[i] = (__bf16)0.f; b1l[i] = (__bf16)0.f;
        }
      }
#pragma unroll
      for (int jj = 0; jj < 4; jj++) {
        if (jj < njt) {
          int jt = jt0 + jj;
          bf16x8 ah = *(const bf16x8*)(W1BTh + (size_t)(jt * 16 + li) * 224 + k0);
          bf16x8 al = *(const bf16x8*)(W1BTl + (size_t)(jt * 16 + li) * 224 + k0);
          acc0[jj] = mfma16(ah, b0h, acc0[jj]);
          acc0[jj] = mfma16(ah, b0l, acc0[jj]);
          acc0[jj] = mfma16(al, b0h, acc0[jj]);
          acc1[jj] = mfma16(ah, b1h, acc1[jj]);
          acc1[jj] = mfma16(ah, b1l, acc1[jj]);
          acc1[jj] = mfma16(al, b1h, acc1[jj]);
        }
      }
    }
    float ev0 = e1[nb + li];
    float ev1 = e1[nb + 16 + li];
#pragma unroll
    for (int jj = 0; jj < 4; jj++) {
      if (jj < njt) {
        int jt = jt0 + jj;
#pragma unroll
        for (int r = 0; r < 4; r++) {
          int j = jt * 16 + q * 4 + r;
          float* pb = pBT + (size_t)j * NODES + nb + li;
          pb[0] = acc0[jj][r];
          pb[16] = acc1[jj][r];
        }
        float s1v[4], s2v[4], s3v[4];
#pragma unroll
        for (int r = 0; r < 4; r++) {
          float a0 = acc0[jj][r], a1 = acc1[jj][r];
          s1v[r] = a0 + a1;
          s2v[r] = fmaf(a0, a0, a1 * a1);
          s3v[r] = fmaf(a0, ev0, a1 * ev1);
        }
#pragma unroll
        for (int o = 8; o > 0; o >>= 1) {
#pragma unroll
          for (int r = 0; r < 4; r++) {
            s1v[r] += __shfl_xor(s1v[r], o);
            s2v[r] += __shfl_xor(s2v[r], o);
            s3v[r] += __shfl_xor(s3v[r], o);
          }
        }
        if (li < 4) {
          float g1 = (li == 0) ? s1v[0] : (li == 1) ? s1v[1] : (li == 2) ? s1v[2] : s1v[3];
          float g2 = (li == 0) ? s2v[0] : (li == 1) ? s2v[1] : (li == 2) ? s2v[2] : s2v[3];
          float g3 = (li == 0) ? s3v[0] : (li == 1) ? s3v[1] : (li == 2) ? s3v[2] : s3v[3];
          int j = jt * 16 + q * 4 + li;
          SB1[(size_t)blk * MID_ + j] = g1;
          SB2[(size_t)blk * MID_ + j] = g2;
          SB3[(size_t)blk * MID_ + j] = g3;
        }
      }
    }
  } else {
    int ab = blk - 1024;           // b*16 + a
    int b = ab >> 4;
    int node = b * N_ + loc[ab];
    for (int i = t; i < MID_; i += 256) xr[i] = xc[(size_t)node * MID_ + i];
    __syncthreads();
    if (t < MID_) {
      float acc = 0.f;
      for (int i = 0; i < MID_; i++) acc = fmaf(xr[i], W1[i * MID_ + t], acc);
      pA[ab * MID_ + t] = acc;
    }
  }
}

// ---------------- fin: one block per feature j — stats from SB partials + BN finalize + vaT + wpack ----------------
__global__ __launch_bounds__(256) void k_fin(const float* __restrict__ SB1,
                                             const float* __restrict__ SB2,
                                             const float* __restrict__ SB3,
                                             const float* __restrict__ pA,
                                             const float* __restrict__ cu,
                                             const float* __restrict__ base,
                                             const float* __restrict__ d1row,
                                             const float* __restrict__ c2row,
                                             const int* __restrict__ loc,
                                             const float* __restrict__ bng,
                                             const float* __restrict__ bnb,
                                             const float* __restrict__ W2,
                                             float* __restrict__ vaT,
                                             float* __restrict__ wpack4) {
  __shared__ float utmp[1536 + 192];
  __shared__ float redm[4];
  __shared__ float reds[4];
  __shared__ float bcast[2];
  int t = threadIdx.x, lane = t & 63, w = t >> 6;
  int j = blockIdx.x;
  float cuj = cu[j], bj = base[j];
  float q1 = 0.f, q2 = 0.f, q3 = 0.f;
#pragma unroll
  for (int c = t * 4; c < t * 4 + 4; c++) {
    q1 += SB1[(size_t)c * MID_ + j];
    q2 += SB2[(size_t)c * MID_ + j];
    q3 += SB3[(size_t)c * MID_ + j];
  }
  float t1 = 0.f, t2 = 0.f, t3 = 0.f;
#pragma unroll
  for (int r = t * 2; r < t * 2 + 2; r++) {
    float pa = pA[r * MID_ + j] + bj;
    t1 += pa;
    t2 = fmaf(pa, pa, t2);
    t3 = fmaf(pa, d1row[loc[r]], t3);
  }
  utmp[0 * 256 + t] = q1;
  utmp[1 * 256 + t] = q2;
  utmp[2 * 256 + t] = q3;
  utmp[3 * 256 + t] = t1;
  utmp[4 * 256 + t] = t2;
  utmp[5 * 256 + t] = t3;
  float p1 = 0.f, p2 = 0.f;
#pragma unroll
  for (int r = t * 2; r < t * 2 + 2; r++) {
    int l = loc[r];
    p1 += d1row[l];
    p2 += c2row[l];
  }
#pragma unroll
  for (int o = 32; o > 0; o >>= 1) { p1 += __shfl_xor(p1, o); p2 += __shfl_xor(p2, o); }
  if (lane == 0) { redm[w] = p1; reds[w] = p2; }
  __syncthreads();
  if (t < 192) {
    int s = t >> 5, b32 = t & 31;
    float ssum = 0.f;
#pragma unroll
    for (int i = 0; i < 8; i++) ssum += utmp[s * 256 + b32 * 8 + i];
    utmp[1536 + s * 32 + b32] = ssum;
  }
  __syncthreads();
  if (t == 0) {
    float Sc1 = (redm[0] + redm[1]) + (redm[2] + redm[3]);
    float Sc2 = (reds[0] + reds[1]) + (reds[2] + reds[3]);
    double T1 = 0, T2 = 0, T3 = 0, cross = 0, sp1 = 0, sp2 = 0, spe = 0;
    for (int b = 0; b < 32; b++) {
      float sq1 = utmp[1536 + 0 * 32 + b];
      float sq2 = utmp[1536 + 1 * 32 + b];
      float sq3 = utmp[1536 + 2 * 32 + b];
      float pt1 = utmp[1536 + 3 * 32 + b];
      float pt2 = utmp[1536 + 4 * 32 + b];
      float pt3 = utmp[1536 + 5 * 32 + b];
      T1 += pt1; T2 += pt2; T3 += pt3;
      cross += (double)pt1 * sq1;
      sp1 += sq1; sp2 += sq2; spe += sq3;
    }
    double s1 = 1024.0 * T1 + 16.0 * sp1 + (double)cuj * Sc1;
    double s2 = 1024.0 * T2 + 16.0 * sp2 + (double)cuj * cuj * Sc2 +
                2.0 * (cross + (double)cuj * (T3 + spe));
    double mu = s1 * (1.0 / (double)ROWS);
    double var = s2 * (1.0 / (double)ROWS) - mu * mu;
    float sc = (float)(1.0 / sqrt(var + 1e-5)) * bng[j];
    float sh = bnb[j] - (float)mu * sc;
    bcast[0] = sc;
    bcast[1] = sh;
    wpack4[4 * j + 0] = sc;
    wpack4[4 * j + 1] = cuj * sc;
    wpack4[4 * j + 2] = W2[j];
    wpack4[4 * j + 3] = 0.f;
  }
  __syncthreads();
  float sc = bcast[0], sh = bcast[1];
#pragma unroll
  for (int r = t * 2; r < t * 2 + 2; r++) {
    int b = r >> 4, a = r & 15;
    float pa = pA[r * MID_ + j] + bj;
    vaT[((size_t)b * MID_ + j) * 16 + a] = pa * sc + sh;
  }
}

// ---------------- logits + fused softmax combine (last block per batch) ----------------
__global__ __launch_bounds__(256) void k_logits(const float* __restrict__ pBT,
                                                const float* __restrict__ vaT,
                                                const float* __restrict__ wpack4,
                                                const float* __restrict__ dist,
                                                const int* __restrict__ loc,
                                                const int* __restrict__ mask,
                                                const float* __restrict__ b2,
                                                float* __restrict__ lg,
                                                float2* __restrict__ Psm,
                                                int* __restrict__ smcnt,
                                                float* __restrict__ out) {
  __shared__ float vaS[MID_ * 16];
  __shared__ float accL[4][8][64];
  __shared__ int loc_s[16];
  __shared__ float redm[4];
  __shared__ float reds[4];
  __shared__ int lastFlag;
  __shared__ float scs[16];
  int t = threadIdx.x, lane = t & 63;
  int w = __builtin_amdgcn_readfirstlane(t >> 6);
  int b = blockIdx.y, nt = blockIdx.x;
  int n0 = nt * 64;
  if (t < 16) loc_s[t] = loc[b * 16 + t];
  for (int i = t; i < MID_ * 16; i += 256) vaS[i] = vaT[(size_t)b * MID_ * 16 + i];
  __syncthreads();
  float c[16];
#pragma unroll
  for (int a = 0; a < 16; a++) c[a] = dist[(size_t)loc_s[a] * N_ + n0 + lane];
  float acc16[16];
#pragma unroll
  for (int a = 0; a < 16; a++) acc16[a] = 0.f;
  const float4* wp = (const float4*)wpack4;
  int ng = b * N_ + n0 + lane;
  int jb = w * 52;
#pragma unroll 4
  for (int jj = 0; jj < 52; jj++) {
    int j = jb + jj;
    float pbv = pBT[(size_t)j * NODES + ng];
    float4 wv = wp[j];
    float pbs = pbv * wv.x;
    const float* va = &vaS[j * 16];
#pragma unroll
    for (int a = 0; a < 16; a++) {
      float h = fmaf(c[a], wv.y, va[a] + pbs);
      h = fmaxf(h, 0.f);
      acc16[a] = fmaf(h, wv.z, acc16[a]);
    }
  }

  float b2v = b2[0];
  float sv[4];
  int ois[4];
  unsigned mk = 0;
#pragma unroll
  for (int half = 0; half < 2; half++) {
#pragma unroll
    for (int a8 = 0; a8 < 8; a8++) accL[t >> 6][a8][lane] = acc16[half * 8 + a8];
    __syncthreads();
#pragma unroll
    for (int p = 0; p < 2; p++) {
      int idx = p * 256 + t;
      int a8 = idx >> 6, nn = idx & 63;
      float s = (accL[0][a8][nn] + accL[1][a8][nn]) +
                (accL[2][a8][nn] + accL[3][a8][nn]) + b2v;
      int a = half * 8 + a8;
      int oi = b * AN_ + a * N_ + n0 + nn;
      int iv = half * 2 + p;
      bool m_ = mask[oi] != 0;
      sv[iv] = m_ ? s : -1e8f;
      ois[iv] = oi;
      mk |= (m_ ? 1u : 0u) << iv;
    }
    __syncthreads();
  }

  float mx = fmaxf(fmaxf(sv[0], sv[1]), fmaxf(sv[2], sv[3]));
#pragma unroll
  for (int o = 32; o > 0; o >>= 1) mx = fmaxf(mx, __shfl_xor(mx, o));
  if (lane == 0) redm[t >> 6] = mx;
  __syncthreads();
  mx = fmaxf(fmaxf(redm[0], redm[1]), fmaxf(redm[2], redm[3]));
  float ssum = 0.f;
#pragma unroll
  for (int iv = 0; iv < 4; iv++) {
    float pv = ((mk >> iv) & 1u) ? expf(sv[iv] - mx) : 0.f;
    lg[ois[iv]] = pv;
    ssum += pv;
  }
#pragma unroll
  for (int o = 32; o > 0; o >>= 1) ssum += __shfl_xor(ssum, o);
  if (lane == 0) reds[t >> 6] = ssum;
  __syncthreads();
  if (t == 0) {
    Psm[b * 16 + nt] = make_float2(mx, (reds[0] + reds[1]) + (reds[2] + reds[3]));
    __threadfence();                       // publish lg slice + Psm partial (device scope)
    unsigned r = atomicAdd((unsigned*)&smcnt[b], 1u);
    lastFlag = (r == 15u) ? 1 : 0;
  }
  __syncthreads();
  if (lastFlag == 0) return;

  // ---- fused sm2: this is the 16th (last) block of batch b ----
  __threadfence();                          // acquire: see all other blocks' lg/Psm
  if (t < 16) {
    float2 pr[16];
    float M = -3.0e38f;
#pragma unroll
    for (int k = 0; k < 16; k++) {
      pr[k] = Psm[b * 16 + k];
      M = fmaxf(M, pr[k].x);
    }
    float S = 0.f;
#pragma unroll
    for (int k = 0; k < 16; k++) S += pr[k].y * expf(pr[k].x - M);
    scs[t] = expf(pr[t].x - M) / S;
  }
  __syncthreads();
  const float* lb = lg + (size_t)b * AN_;
  float* ob = out + (size_t)b * AN_;
  for (int i = t; i < AN_; i += 256) {
    int n = i & 1023;
    ob[i] = lb[i] * scs[n >> 6];
  }
}

extern "C" void kernel_launch(void* const* d_in, const int* in_sizes, int n_in,
                              void* d_out, int out_size, void* d_ws, size_t ws_size,
                              hipStream_t stream) {
  const float* gn = (const float*)d_in[0];
  const int* el = (const int*)d_in[1];
  const int* loc = (const int*)d_in[2];
  const int* mask = (const int*)d_in[3];
  const float* dist = (const float*)d_in[4];
  const float* c0W = (const float*)d_in[5];
  const float* c0b = (const float*)d_in[6];
  const float* c0g = (const float*)d_in[7];
  const float* c0be = (const float*)d_in[8];
  const float* c1W = (const float*)d_in[9];
  const float* c1b = (const float*)d_in[10];
  const float* c1g = (const float*)d_in[11];
  const float* c1be = (const float*)d_in[12];
  const float* c2W = (const float*)d_in[13];
  const float* c2b = (const float*)d_in[14];
  const float* c2g = (const float*)d_in[15];
  const float* c2be = (const float*)d_in[16];
  const float* eW = (const float*)d_in[17];
  const float* eb = (const float*)d_in[18];
  const float* W1 = (const float*)d_in[19];
  const float* b1 = (const float*)d_in[20];
  const float* bng = (const float*)d_in[21];
  const float* bnb = (const float*)d_in[22];
  const float* W2 = (const float*)d_in[23];
  const float* b2 = (const float*)d_in[24];
  float* out = (float*)d_out;

  char* p = (char*)d_ws;
  auto alloc = [&](size_t bytes) {
    char* r = p;
    p += (bytes + 255) & ~(size_t)255;
    return r;
  };
  int* counts = (int*)alloc((size_t)NODES * 4);
  int* rowptr = (int*)alloc((size_t)NODES * 4);
  int* ssrc = (int*)alloc((size_t)NEDGE * 4);
  float* xc = (float*)alloc((size_t)NODES * MID_ * 4);
  float* pBT = (float*)alloc((size_t)NODES * MID_ * 4);
  float* pA = (float*)alloc((size_t)512 * MID_ * 4);
  float* cu = (float*)alloc(256 * 4);
  float* base = (float*)alloc(256 * 4);
  float* d1row = (float*)alloc((size_t)N_ * 4);
  float* c2row = (float*)alloc((size_t)N_ * 4);
  float* e1 = (float*)alloc((size_t)B_ * N_ * 4);
  float* vaT = (float*)alloc((size_t)B_ * MID_ * 16 * 4);
  float* wpack4 = (float*)alloc((size_t)MID_ * 4 * 4);
  float* lg = (float*)alloc((size_t)ROWS * 4);
  float2* Psm = (float2*)alloc((size_t)B_ * 16 * 8);
  __bf16* W1BTh = (__bf16*)alloc((size_t)MID_ * 224 * 2);
  __bf16* W1BTl = (__bf16*)alloc((size_t)MID_ * 224 * 2);
  float* SB1 = (float*)alloc((size_t)1024 * MID_ * 4);
  float* SB2 = (float*)alloc((size_t)1024 * MID_ * 4);
  float* SB3 = (float*)alloc((size_t)1024 * MID_ * 4);
  int* smcnt = (int*)alloc(32 * 4);

  k_front<<<529, 256, 0, stream>>>(el, dist, loc, W1, eW, eb, b1,
                                   rowptr, counts, ssrc, d1row, c2row, e1, cu, base,
                                   W1BTh, W1BTl, smcnt);

  k_layer<16, true><<<1024, 256, 0, stream>>>(gn, FIN_, 0, xc, 16, rowptr, counts, ssrc, c0W, c0b, c0g, c0be);
  k_layer<64, false><<<1024, 256, 0, stream>>>(xc, MID_, 16, xc, 80, rowptr, counts, ssrc, c1W, c1b, c1g, c1be);
  k_layer<64, false><<<1024, 256, 0, stream>>>(xc, MID_, 80, xc, 144, rowptr, counts, ssrc, c2W, c2b, c2g, c2be);

  k_p1<<<1536, 256, 0, stream>>>(xc, W1, W1BTh, W1BTl, e1, loc, pBT, pA, SB1, SB2, SB3);
  k_fin<<<208, 256, 0, stream>>>(SB1, SB2, SB3, pA, cu, base, d1row, c2row, loc, bng, bnb, W2, vaT, wpack4);

  k_logits<<<dim3(16, 32), 256, 0, stream>>>(pBT, vaT, wpack4, dist, loc, mask, b2, lg, Psm, smcnt, out);
}

// Round 6
// 244.132 us; speedup vs baseline: 4.4979x; 1.1944x over previous
//
#include <hip/hip_runtime.h>
#include <cstddef>

#define B_    32
#define N_    1024
#define E_    4096
#define A_    16
#define FIN_  16
#define H_    64
#define MID_  208
#define NODES (B_ * N_)      // 32768
#define NEDGE (B_ * E_)      // 131072
#define ROWS  (B_ * A_ * N_) // 524288
#define AN_   (A_ * N_)      // 16384

__device__ __forceinline__ float readlane_f(float v, int l) {
  return __uint_as_float(__builtin_amdgcn_readlane(__float_as_uint(v), l));
}

typedef __attribute__((ext_vector_type(8))) __bf16 bf16x8;
typedef __attribute__((ext_vector_type(4))) float f32x4;

__device__ __forceinline__ f32x4 mfma16(bf16x8 a, bf16x8 b, f32x4 c) {
  return __builtin_amdgcn_mfma_f32_16x16x32_bf16(a, b, c, 0, 0, 0);
}

// split 8 consecutive fp32 into bf16 hi + lo fragments (error ~2^-18 rel)
__device__ __forceinline__ void cvt8(const float* __restrict__ p, bf16x8& hi, bf16x8& lo) {
  float4 v0 = *(const float4*)p;
  float4 v1 = *(const float4*)(p + 4);
  float vv[8] = {v0.x, v0.y, v0.z, v0.w, v1.x, v1.y, v1.z, v1.w};
#pragma unroll
  for (int i = 0; i < 8; i++) {
    __bf16 h = (__bf16)vv[i];
    hi[i] = h;
    lo[i] = (__bf16)(vv[i] - (float)h);
  }
}

// ---------------- front: per-graph CSR in-block (LDS-staged ssrc) + d1 + csum + cu + W1B^T->bf16 ----------------
__global__ __launch_bounds__(256) void k_front(const int* __restrict__ el,
                                               const float* __restrict__ dist,
                                               const int* __restrict__ loc,
                                               const float* __restrict__ W1,
                                               const float* __restrict__ eW,
                                               const float* __restrict__ eb,
                                               const float* __restrict__ b1,
                                               int* __restrict__ rowptr,
                                               int* __restrict__ counts,
                                               int* __restrict__ ssrc,
                                               float* __restrict__ d1row,
                                               float* __restrict__ c2row,
                                               float* __restrict__ e1,
                                               float* __restrict__ cu,
                                               float* __restrict__ base,
                                               __bf16* __restrict__ W1BTh,
                                               __bf16* __restrict__ W1BTl) {
  __shared__ int cnt[1024];
  __shared__ int cur[1024];
  __shared__ int part[256];
  __shared__ int ssrcS[4096];
  __shared__ int loc_s[16];
  int blk = blockIdx.x, t = threadIdx.x;
  if (blk < 32) {
    int b = blk;
    for (int i = t; i < 1024; i += 256) cnt[i] = 0;
    __syncthreads();
    const int* srcp = el + b * (2 * E_);
    const int* dstp = srcp + E_;
    for (int i = t; i < E_; i += 256) atomicAdd(&cnt[dstp[i]], 1);
    __syncthreads();
    int4 c4 = *(const int4*)&cnt[t * 4];
    int s = c4.x + c4.y + c4.z + c4.w;
    part[t] = s;
    __syncthreads();
    for (int off = 1; off < 256; off <<= 1) {
      int v = (t >= off) ? part[t - off] : 0;
      __syncthreads();
      part[t] += v;
      __syncthreads();
    }
    int prev = (t == 0) ? 0 : part[t - 1];
    int p0 = prev, p1 = p0 + c4.x, p2 = p1 + c4.y, p3 = p2 + c4.z;
    *(int4*)&rowptr[b * 1024 + t * 4] = make_int4(p0 + b * E_, p1 + b * E_, p2 + b * E_, p3 + b * E_);
    *(int4*)&counts[b * 1024 + t * 4] = c4;
    cur[t * 4 + 0] = p0;
    cur[t * 4 + 1] = p1;
    cur[t * 4 + 2] = p2;
    cur[t * 4 + 3] = p3;
    __syncthreads();
    for (int i = t; i < E_; i += 256) {
      int dl = dstp[i];
      int sl = srcp[i];
      int pos = atomicAdd(&cur[dl], 1);
      ssrcS[pos] = b * N_ + sl;
    }
    __syncthreads();
    for (int i = t; i < E_; i += 256) ssrc[b * E_ + i] = ssrcS[i];
  } else if (blk < 288) {
    int lane = t & 63, w = t >> 6;
    int r = (blk - 32) * 4 + w;
    const float* dr = dist + (size_t)r * N_;
    float s = 0.f, c2 = 0.f;
#pragma unroll
    for (int k = 0; k < 16; k++) {
      float v = dr[lane + 64 * k];
      s += v;
      c2 = fmaf(v, v, c2);
    }
#pragma unroll
    for (int o = 32; o > 0; o >>= 1) { s += __shfl_xor(s, o); c2 += __shfl_xor(c2, o); }
    if (lane == 0) { d1row[r] = s; c2row[r] = c2; }
  } else if (blk < 320) {
    int b = blk - 288;
    if (t < 16) loc_s[t] = loc[b * 16 + t];
    __syncthreads();
    float e4[4] = {0.f, 0.f, 0.f, 0.f};
    for (int a = 0; a < 16; a++) {
      const float* dr = dist + (size_t)loc_s[a] * N_;
#pragma unroll
      for (int k = 0; k < 4; k++) e4[k] += dr[t + 256 * k];
    }
#pragma unroll
    for (int k = 0; k < 4; k++) e1[b * N_ + t + 256 * k] = e4[k];
  } else if (blk == 320) {
    int j = t;
    if (j < MID_) {
      float c = 0.f, bs = 0.f;
      for (int k = 0; k < H_; k++) {
        float w = W1[(2 * MID_ + k) * MID_ + j];
        c = fmaf(eW[k], w, c);
        bs = fmaf(eb[k], w, bs);
      }
      cu[j] = c;
      base[j] = bs + b1[j];
    }
  } else {
    // W1B^T conversion to bf16 hi/lo, row j = blk-321, k padded to 224 with zeros
    int jr = blk - 321;
    if (t < 224) {
      float v = (t < MID_) ? W1[(size_t)(MID_ + t) * MID_ + jr] : 0.f;
      __bf16 h = (__bf16)v;
      W1BTh[jr * 224 + t] = h;
      W1BTl[jr * 224 + t] = (__bf16)(v - (float)h);
    }
  }
}

// ---------------- GIN layer: XCD-swizzled blocks; wave per 8 nodes ----------------
template <int FINT, bool COPYIN>
__global__ __launch_bounds__(256) void k_layer(const float* __restrict__ xin, int xstride, int in_off,
                                               float* __restrict__ xc, int out_off,
                                               const int* __restrict__ rowptr,
                                               const int* __restrict__ counts,
                                               const int* __restrict__ ssrc,
                                               const float* __restrict__ W,
                                               const float* __restrict__ bias,
                                               const float* __restrict__ g,
                                               const float* __restrict__ beta) {
  int t = threadIdx.x, lane = t & 63, w = t >> 6;
  float Wcol[FINT];
#pragma unroll
  for (int f = 0; f < FINT; f++) Wcol[f] = W[f * 64 + lane];
  float bv = bias[lane], gv = g[lane], bev = beta[lane];
  constexpr int CH = 64 / FINT;
  int f = lane & (FINT - 1);
  int ch = (FINT == 64) ? 0 : (lane >> 4);
  int blk = blockIdx.x;
  int xcd = blk & 7, kk = blk >> 3;
  int graph = xcd * 4 + (kk >> 5);
  int nblk = kk & 31;
  int nbase = graph * N_ + nblk * 32 + w * 8;

  float agg[8];
#pragma unroll
  for (int nn = 0; nn < 8; nn++) {
    int node = nbase + nn;
    int r0 = rowptr[node];
    int deg = counts[node];
    float a0 = 0.f, a1 = 0.f, a2 = 0.f, a3 = 0.f;
    int e = ch;
    for (; e + 3 * CH < deg; e += 4 * CH) {
      int s0 = ssrc[r0 + e];
      int s1 = ssrc[r0 + e + CH];
      int s2 = ssrc[r0 + e + 2 * CH];
      int s3 = ssrc[r0 + e + 3 * CH];
      a0 += xin[(size_t)s0 * xstride + in_off + f];
      a1 += xin[(size_t)s1 * xstride + in_off + f];
      a2 += xin[(size_t)s2 * xstride + in_off + f];
      a3 += xin[(size_t)s3 * xstride + in_off + f];
    }
    for (; e < deg; e += CH) {
      int s = ssrc[r0 + e];
      a0 += xin[(size_t)s * xstride + in_off + f];
    }
    agg[nn] = (a0 + a1) + (a2 + a3);
  }

#pragma unroll
  for (int nn = 0; nn < 8; nn++) {
    int node = nbase + nn;
    float aggf = agg[nn];
    float y0 = bv, y1 = 0.f, y2 = 0.f, y3 = 0.f;
#pragma unroll
    for (int l = 0; l < 64; l += 4) {
      y0 = fmaf(readlane_f(aggf, l + 0), Wcol[(l + 0) & (FINT - 1)], y0);
      y1 = fmaf(readlane_f(aggf, l + 1), Wcol[(l + 1) & (FINT - 1)], y1);
      y2 = fmaf(readlane_f(aggf, l + 2), Wcol[(l + 2) & (FINT - 1)], y2);
      y3 = fmaf(readlane_f(aggf, l + 3), Wcol[(l + 3) & (FINT - 1)], y3);
    }
    float y = (y0 + y1) + (y2 + y3);
    float m = y;
#pragma unroll
    for (int o = 32; o > 0; o >>= 1) m += __shfl_xor(m, o);
    m *= (1.f / 64.f);
    float d = y - m;
    float vv = d * d;
#pragma unroll
    for (int o = 32; o > 0; o >>= 1) vv += __shfl_xor(vv, o);
    vv *= (1.f / 64.f);
    float outv = fmaxf(d * rsqrtf(vv + 1e-5f) * gv + bev, 0.f);
    xc[(size_t)node * MID_ + out_off + lane] = outv;
    if (COPYIN) {
      if (lane < FIN_) xc[(size_t)node * MID_ + lane] = xin[(size_t)node * FIN_ + lane];
    }
  }
}

// ---------------- p1: blk<1024: MFMA GEMM pBT (bf16 hi/lo split) + in-register column stats; blk>=1024: pA ----------------
__global__ __launch_bounds__(256) void k_p1(const float* __restrict__ xc,
                                            const float* __restrict__ W1,
                                            const __bf16* __restrict__ W1BTh,
                                            const __bf16* __restrict__ W1BTl,
                                            const float* __restrict__ e1,
                                            const int* __restrict__ loc,
                                            float* __restrict__ pBT,
                                            float* __restrict__ pA,
                                            float* __restrict__ SB1,
                                            float* __restrict__ SB2,
                                            float* __restrict__ SB3) {
  __shared__ float xr[MID_];
  int t = threadIdx.x, lane = t & 63;
  int w = t >> 6;
  int blk = blockIdx.x;
  if (blk < 1024) {
    int nb = blk * 32;
    int q = lane >> 4, li = lane & 15;
    int jt0 = (w == 0) ? 0 : (w == 1) ? 4 : (w == 2) ? 7 : 10;
    int njt = (w == 0) ? 4 : 3;
    f32x4 zero4 = {0.f, 0.f, 0.f, 0.f};
    f32x4 acc0[4], acc1[4];
#pragma unroll
    for (int i = 0; i < 4; i++) { acc0[i] = zero4; acc1[i] = zero4; }
    const float* xr0 = xc + (size_t)(nb + li) * MID_;
    const float* xr1 = xc + (size_t)(nb + 16 + li) * MID_;
    for (int kc = 0; kc < 7; kc++) {
      int k0 = kc * 32 + q * 8;
      bf16x8 b0h, b0l, b1h, b1l;
      if (k0 < MID_) {
        cvt8(xr0 + k0, b0h, b0l);
        cvt8(xr1 + k0, b1h, b1l);
      } else {
#pragma unroll
        for (int i = 0; i < 8; i++) {
          b0h[i] = (__bf16)0.f; b0l[i] = (__bf16)0.f;
          b1h[i] = (__bf16)0.f; b1l[i] = (__bf16)0.f;
        }
      }
#pragma unroll
      for (int jj = 0; jj < 4; jj++) {
        if (jj < njt) {
          int jt = jt0 + jj;
          bf16x8 ah = *(const bf16x8*)(W1BTh + (size_t)(jt * 16 + li) * 224 + k0);
          bf16x8 al = *(const bf16x8*)(W1BTl + (size_t)(jt * 16 + li) * 224 + k0);
          acc0[jj] = mfma16(ah, b0h, acc0[jj]);
          acc0[jj] = mfma16(ah, b0l, acc0[jj]);
          acc0[jj] = mfma16(al, b0h, acc0[jj]);
          acc1[jj] = mfma16(ah, b1h, acc1[jj]);
          acc1[jj] = mfma16(ah, b1l, acc1[jj]);
          acc1[jj] = mfma16(al, b1h, acc1[jj]);
        }
      }
    }
    float ev0 = e1[nb + li];
    float ev1 = e1[nb + 16 + li];
#pragma unroll
    for (int jj = 0; jj < 4; jj++) {
      if (jj < njt) {
        int jt = jt0 + jj;
#pragma unroll
        for (int r = 0; r < 4; r++) {
          int j = jt * 16 + q * 4 + r;
          float* pb = pBT + (size_t)j * NODES + nb + li;
          pb[0] = acc0[jj][r];
          pb[16] = acc1[jj][r];
        }
        float s1v[4], s2v[4], s3v[4];
#pragma unroll
        for (int r = 0; r < 4; r++) {
          float a0 = acc0[jj][r], a1 = acc1[jj][r];
          s1v[r] = a0 + a1;
          s2v[r] = fmaf(a0, a0, a1 * a1);
          s3v[r] = fmaf(a0, ev0, a1 * ev1);
        }
#pragma unroll
        for (int o = 8; o > 0; o >>= 1) {
#pragma unroll
          for (int r = 0; r < 4; r++) {
            s1v[r] += __shfl_xor(s1v[r], o);
            s2v[r] += __shfl_xor(s2v[r], o);
            s3v[r] += __shfl_xor(s3v[r], o);
          }
        }
        if (li < 4) {
          float g1 = (li == 0) ? s1v[0] : (li == 1) ? s1v[1] : (li == 2) ? s1v[2] : s1v[3];
          float g2 = (li == 0) ? s2v[0] : (li == 1) ? s2v[1] : (li == 2) ? s2v[2] : s2v[3];
          float g3 = (li == 0) ? s3v[0] : (li == 1) ? s3v[1] : (li == 2) ? s3v[2] : s3v[3];
          int j = jt * 16 + q * 4 + li;
          SB1[(size_t)blk * MID_ + j] = g1;
          SB2[(size_t)blk * MID_ + j] = g2;
          SB3[(size_t)blk * MID_ + j] = g3;
        }
      }
    }
  } else {
    int ab = blk - 1024;           // b*16 + a
    int b = ab >> 4;
    int node = b * N_ + loc[ab];
    for (int i = t; i < MID_; i += 256) xr[i] = xc[(size_t)node * MID_ + i];
    __syncthreads();
    if (t < MID_) {
      float acc = 0.f;
      for (int i = 0; i < MID_; i++) acc = fmaf(xr[i], W1[i * MID_ + t], acc);
      pA[ab * MID_ + t] = acc;
    }
  }
}

// ---------------- fin: one block per feature j — stats from SB partials + BN finalize + vaT + wpack ----------------
__global__ __launch_bounds__(256) void k_fin(const float* __restrict__ SB1,
                                             const float* __restrict__ SB2,
                                             const float* __restrict__ SB3,
                                             const float* __restrict__ pA,
                                             const float* __restrict__ cu,
                                             const float* __restrict__ base,
                                             const float* __restrict__ d1row,
                                             const float* __restrict__ c2row,
                                             const int* __restrict__ loc,
                                             const float* __restrict__ bng,
                                             const float* __restrict__ bnb,
                                             const float* __restrict__ W2,
                                             float* __restrict__ vaT,
                                             float* __restrict__ wpack4) {
  __shared__ float utmp[1536 + 192];
  __shared__ float redm[4];
  __shared__ float reds[4];
  __shared__ float bcast[2];
  int t = threadIdx.x, lane = t & 63, w = t >> 6;
  int j = blockIdx.x;
  float cuj = cu[j], bj = base[j];
  float q1 = 0.f, q2 = 0.f, q3 = 0.f;
#pragma unroll
  for (int c = t * 4; c < t * 4 + 4; c++) {
    q1 += SB1[(size_t)c * MID_ + j];
    q2 += SB2[(size_t)c * MID_ + j];
    q3 += SB3[(size_t)c * MID_ + j];
  }
  float t1 = 0.f, t2 = 0.f, t3 = 0.f;
#pragma unroll
  for (int r = t * 2; r < t * 2 + 2; r++) {
    float pa = pA[r * MID_ + j] + bj;
    t1 += pa;
    t2 = fmaf(pa, pa, t2);
    t3 = fmaf(pa, d1row[loc[r]], t3);
  }
  utmp[0 * 256 + t] = q1;
  utmp[1 * 256 + t] = q2;
  utmp[2 * 256 + t] = q3;
  utmp[3 * 256 + t] = t1;
  utmp[4 * 256 + t] = t2;
  utmp[5 * 256 + t] = t3;
  float p1 = 0.f, p2 = 0.f;
#pragma unroll
  for (int r = t * 2; r < t * 2 + 2; r++) {
    int l = loc[r];
    p1 += d1row[l];
    p2 += c2row[l];
  }
#pragma unroll
  for (int o = 32; o > 0; o >>= 1) { p1 += __shfl_xor(p1, o); p2 += __shfl_xor(p2, o); }
  if (lane == 0) { redm[w] = p1; reds[w] = p2; }
  __syncthreads();
  if (t < 192) {
    int s = t >> 5, b32 = t & 31;
    float ssum = 0.f;
#pragma unroll
    for (int i = 0; i < 8; i++) ssum += utmp[s * 256 + b32 * 8 + i];
    utmp[1536 + s * 32 + b32] = ssum;
  }
  __syncthreads();
  if (t == 0) {
    float Sc1 = (redm[0] + redm[1]) + (redm[2] + redm[3]);
    float Sc2 = (reds[0] + reds[1]) + (reds[2] + reds[3]);
    double T1 = 0, T2 = 0, T3 = 0, cross = 0, sp1 = 0, sp2 = 0, spe = 0;
    for (int b = 0; b < 32; b++) {
      float sq1 = utmp[1536 + 0 * 32 + b];
      float sq2 = utmp[1536 + 1 * 32 + b];
      float sq3 = utmp[1536 + 2 * 32 + b];
      float pt1 = utmp[1536 + 3 * 32 + b];
      float pt2 = utmp[1536 + 4 * 32 + b];
      float pt3 = utmp[1536 + 5 * 32 + b];
      T1 += pt1; T2 += pt2; T3 += pt3;
      cross += (double)pt1 * sq1;
      sp1 += sq1; sp2 += sq2; spe += sq3;
    }
    double s1 = 1024.0 * T1 + 16.0 * sp1 + (double)cuj * Sc1;
    double s2 = 1024.0 * T2 + 16.0 * sp2 + (double)cuj * cuj * Sc2 +
                2.0 * (cross + (double)cuj * (T3 + spe));
    double mu = s1 * (1.0 / (double)ROWS);
    double var = s2 * (1.0 / (double)ROWS) - mu * mu;
    float sc = (float)(1.0 / sqrt(var + 1e-5)) * bng[j];
    float sh = bnb[j] - (float)mu * sc;
    bcast[0] = sc;
    bcast[1] = sh;
    wpack4[4 * j + 0] = sc;
    wpack4[4 * j + 1] = cuj * sc;
    wpack4[4 * j + 2] = W2[j];
    wpack4[4 * j + 3] = 0.f;
  }
  __syncthreads();
  float sc = bcast[0], sh = bcast[1];
#pragma unroll
  for (int r = t * 2; r < t * 2 + 2; r++) {
    int b = r >> 4, a = r & 15;
    float pa = pA[r * MID_ + j] + bj;
    vaT[((size_t)b * MID_ + j) * 16 + a] = pa * sc + sh;
  }
}

// ---------------- logits: 512 threads (8 waves x 26 j's) for 2x occupancy; + softmax partials ----------------
__global__ __launch_bounds__(512) void k_logits(const float* __restrict__ pBT,
                                                const float* __restrict__ vaT,
                                                const float* __restrict__ wpack4,
                                                const float* __restrict__ dist,
                                                const int* __restrict__ loc,
                                                const int* __restrict__ mask,
                                                const float* __restrict__ b2,
                                                float* __restrict__ lg,
                                                float2* __restrict__ Psm) {
  __shared__ float vaS[MID_ * 16];
  __shared__ float accL[8][8][64];
  __shared__ int loc_s[16];
  __shared__ float redm[8];
  __shared__ float reds[8];
  int t = threadIdx.x, lane = t & 63;
  int w = __builtin_amdgcn_readfirstlane(t >> 6);   // 0..7
  int b = blockIdx.y, nt = blockIdx.x;
  int n0 = nt * 64;
  if (t < 16) loc_s[t] = loc[b * 16 + t];
  for (int i = t; i < MID_ * 16; i += 512) vaS[i] = vaT[(size_t)b * MID_ * 16 + i];
  __syncthreads();
  float c[16];
#pragma unroll
  for (int a = 0; a < 16; a++) c[a] = dist[(size_t)loc_s[a] * N_ + n0 + lane];
  float acc16[16];
#pragma unroll
  for (int a = 0; a < 16; a++) acc16[a] = 0.f;
  const float4* wp = (const float4*)wpack4;
  int ng = b * N_ + n0 + lane;
  int jb = w * 26;
#pragma unroll 2
  for (int jj = 0; jj < 26; jj++) {
    int j = jb + jj;
    float pbv = pBT[(size_t)j * NODES + ng];
    float4 wv = wp[j];
    float pbs = pbv * wv.x;
    const float* va = &vaS[j * 16];
#pragma unroll
    for (int a = 0; a < 16; a++) {
      float h = fmaf(c[a], wv.y, va[a] + pbs);
      h = fmaxf(h, 0.f);
      acc16[a] = fmaf(h, wv.z, acc16[a]);
    }
  }

  float b2v = b2[0];
  float sv[2];
  int ois[2];
  unsigned mk = 0;
#pragma unroll
  for (int half = 0; half < 2; half++) {
#pragma unroll
    for (int a8 = 0; a8 < 8; a8++) accL[t >> 6][a8][lane] = acc16[half * 8 + a8];
    __syncthreads();
    {
      int a8 = t >> 6, nn = t & 63;
      float s = b2v;
#pragma unroll
      for (int ww = 0; ww < 8; ww++) s += accL[ww][a8][nn];
      int a = half * 8 + a8;
      int oi = b * AN_ + a * N_ + n0 + nn;
      bool m_ = mask[oi] != 0;
      sv[half] = m_ ? s : -1e8f;
      ois[half] = oi;
      mk |= (m_ ? 1u : 0u) << half;
    }
    __syncthreads();
  }

  float mx = fmaxf(sv[0], sv[1]);
#pragma unroll
  for (int o = 32; o > 0; o >>= 1) mx = fmaxf(mx, __shfl_xor(mx, o));
  if (lane == 0) redm[t >> 6] = mx;
  __syncthreads();
  mx = fmaxf(fmaxf(fmaxf(redm[0], redm[1]), fmaxf(redm[2], redm[3])),
             fmaxf(fmaxf(redm[4], redm[5]), fmaxf(redm[6], redm[7])));
  float ssum = 0.f;
#pragma unroll
  for (int iv = 0; iv < 2; iv++) {
    float pv = ((mk >> iv) & 1u) ? expf(sv[iv] - mx) : 0.f;
    lg[ois[iv]] = pv;
    ssum += pv;
  }
#pragma unroll
  for (int o = 32; o > 0; o >>= 1) ssum += __shfl_xor(ssum, o);
  if (lane == 0) reds[t >> 6] = ssum;
  __syncthreads();
  if (t == 0) {
    float S = ((reds[0] + reds[1]) + (reds[2] + reds[3])) +
              ((reds[4] + reds[5]) + (reds[6] + reds[7]));
    Psm[b * 16 + nt] = make_float2(mx, S);
  }
}

// ---------------- sm2: combine 16 block-partials per batch, normalize ----------------
__global__ __launch_bounds__(256) void k_sm2(const float* __restrict__ lg,
                                             const float2* __restrict__ P,
                                             float* __restrict__ out) {
  __shared__ float scs[16];
  int b = blockIdx.y, x = blockIdx.x, t = threadIdx.x;
  float M = -3.0e38f;
  float2 pr[16];
#pragma unroll
  for (int k = 0; k < 16; k++) {
    pr[k] = P[b * 16 + k];
    M = fmaxf(M, pr[k].x);
  }
  float S = 0.f;
#pragma unroll
  for (int k = 0; k < 16; k++) S += pr[k].y * expf(pr[k].x - M);
  float inv = 1.0f / S;
  if (t < 16) scs[t] = expf(pr[t].x - M) * inv;
  __syncthreads();
  const float* lb = lg + b * AN_ + x * 2048;
  float* ob = out + b * AN_ + x * 2048;
#pragma unroll
  for (int k = 0; k < 8; k++) {
    int i = t + 256 * k;
    int n = (x * 2048 + i) & 1023;
    ob[i] = lb[i] * scs[n >> 6];
  }
}

extern "C" void kernel_launch(void* const* d_in, const int* in_sizes, int n_in,
                              void* d_out, int out_size, void* d_ws, size_t ws_size,
                              hipStream_t stream) {
  const float* gn = (const float*)d_in[0];
  const int* el = (const int*)d_in[1];
  const int* loc = (const int*)d_in[2];
  const int* mask = (const int*)d_in[3];
  const float* dist = (const float*)d_in[4];
  const float* c0W = (const float*)d_in[5];
  const float* c0b = (const float*)d_in[6];
  const float* c0g = (const float*)d_in[7];
  const float* c0be = (const float*)d_in[8];
  const float* c1W = (const float*)d_in[9];
  const float* c1b = (const float*)d_in[10];
  const float* c1g = (const float*)d_in[11];
  const float* c1be = (const float*)d_in[12];
  const float* c2W = (const float*)d_in[13];
  const float* c2b = (const float*)d_in[14];
  const float* c2g = (const float*)d_in[15];
  const float* c2be = (const float*)d_in[16];
  const float* eW = (const float*)d_in[17];
  const float* eb = (const float*)d_in[18];
  const float* W1 = (const float*)d_in[19];
  const float* b1 = (const float*)d_in[20];
  const float* bng = (const float*)d_in[21];
  const float* bnb = (const float*)d_in[22];
  const float* W2 = (const float*)d_in[23];
  const float* b2 = (const float*)d_in[24];
  float* out = (float*)d_out;

  char* p = (char*)d_ws;
  auto alloc = [&](size_t bytes) {
    char* r = p;
    p += (bytes + 255) & ~(size_t)255;
    return r;
  };
  int* counts = (int*)alloc((size_t)NODES * 4);
  int* rowptr = (int*)alloc((size_t)NODES * 4);
  int* ssrc = (int*)alloc((size_t)NEDGE * 4);
  float* xc = (float*)alloc((size_t)NODES * MID_ * 4);
  float* pBT = (float*)alloc((size_t)NODES * MID_ * 4);
  float* pA = (float*)alloc((size_t)512 * MID_ * 4);
  float* cu = (float*)alloc(256 * 4);
  float* base = (float*)alloc(256 * 4);
  float* d1row = (float*)alloc((size_t)N_ * 4);
  float* c2row = (float*)alloc((size_t)N_ * 4);
  float* e1 = (float*)alloc((size_t)B_ * N_ * 4);
  float* vaT = (float*)alloc((size_t)B_ * MID_ * 16 * 4);
  float* wpack4 = (float*)alloc((size_t)MID_ * 4 * 4);
  float* lg = (float*)alloc((size_t)ROWS * 4);
  float2* Psm = (float2*)alloc((size_t)B_ * 16 * 8);
  __bf16* W1BTh = (__bf16*)alloc((size_t)MID_ * 224 * 2);
  __bf16* W1BTl = (__bf16*)alloc((size_t)MID_ * 224 * 2);
  float* SB1 = (float*)alloc((size_t)1024 * MID_ * 4);
  float* SB2 = (float*)alloc((size_t)1024 * MID_ * 4);
  float* SB3 = (float*)alloc((size_t)1024 * MID_ * 4);

  k_front<<<529, 256, 0, stream>>>(el, dist, loc, W1, eW, eb, b1,
                                   rowptr, counts, ssrc, d1row, c2row, e1, cu, base,
                                   W1BTh, W1BTl);

  k_layer<16, true><<<1024, 256, 0, stream>>>(gn, FIN_, 0, xc, 16, rowptr, counts, ssrc, c0W, c0b, c0g, c0be);
  k_layer<64, false><<<1024, 256, 0, stream>>>(xc, MID_, 16, xc, 80, rowptr, counts, ssrc, c1W, c1b, c1g, c1be);
  k_layer<64, false><<<1024, 256, 0, stream>>>(xc, MID_, 80, xc, 144, rowptr, counts, ssrc, c2W, c2b, c2g, c2be);

  k_p1<<<1536, 256, 0, stream>>>(xc, W1, W1BTh, W1BTl, e1, loc, pBT, pA, SB1, SB2, SB3);
  k_fin<<<208, 256, 0, stream>>>(SB1, SB2, SB3, pA, cu, base, d1row, c2row, loc, bng, bnb, W2, vaT, wpack4);

  k_logits<<<dim3(16, 32), 512, 0, stream>>>(pBT, vaT, wpack4, dist, loc, mask, b2, lg, Psm);
  k_sm2<<<dim3(8, 32), 256, 0, stream>>>(lg, Psm, out);
}